// Round 2
// baseline (197.439 us; speedup 1.0000x reference)
//
#include <hip/hip_runtime.h>
#include <cmath>

// Shapes:
//  fused  [16,64,128,128] f32
//  hf1    [16, 9,256,256] f32
//  hf2    [16, 9,128,128] f32
//  conv_w [3,64,3,3] f32, conv_b [3] f32
//  out    [16,3,512,512] f32
//
// Stage 1 (kernel A): ll = tanh(conv3x3(fused) + b)  -> d_ws  [16,3,128,128]
// Stage 2 (kernel B): out = iwt(iwt(ll, hf2), hf1)   fused, no 256x256 intermediate.

#define H1 128
#define W1 128
#define H2 256
#define W2 256
#define H3 512
#define W3 512
#define IN_CH 64

__global__ __launch_bounds__(256) void conv_tanh_kernel(
    const float* __restrict__ fused,
    const float* __restrict__ cw,
    const float* __restrict__ cb,
    float* __restrict__ ll)
{
    // block (64,4): tx covers 2 w-pixels each (w0 = 2*tx), ty covers 4 rows.
    // grid (1, 32, 16)
    const int tx = threadIdx.x;
    const int ty = threadIdx.y;
    const int h  = blockIdx.y * 4 + ty;
    const int b  = blockIdx.z;
    const int w0 = tx * 2;

    float acc[3][2];
    #pragma unroll
    for (int oc = 0; oc < 3; ++oc) { acc[oc][0] = 0.f; acc[oc][1] = 0.f; }

    const float* fb = fused + ((size_t)b * IN_CH) * H1 * W1;

    for (int ic = 0; ic < IN_CH; ++ic) {
        const float* fc = fb + ic * H1 * W1;
        float v[3][4];
        #pragma unroll
        for (int r = 0; r < 3; ++r) {
            const int hh = h + r - 1;
            const bool hv = (hh >= 0) && (hh < H1);
            const float* row = fc + hh * W1;
            v[r][0] = (hv && (w0 > 0)) ? row[w0 - 1] : 0.f;
            if (hv) {
                float2 m = *(const float2*)(row + w0);
                v[r][1] = m.x; v[r][2] = m.y;
            } else {
                v[r][1] = 0.f; v[r][2] = 0.f;
            }
            v[r][3] = (hv && ((w0 + 2) < W1)) ? row[w0 + 2] : 0.f;
        }
        #pragma unroll
        for (int oc = 0; oc < 3; ++oc) {
            const float* wp = cw + (oc * IN_CH + ic) * 9;   // wave-uniform -> s_load
            #pragma unroll
            for (int kh = 0; kh < 3; ++kh) {
                #pragma unroll
                for (int kw = 0; kw < 3; ++kw) {
                    const float wv = wp[kh * 3 + kw];
                    acc[oc][0] = fmaf(v[kh][kw],     wv, acc[oc][0]);
                    acc[oc][1] = fmaf(v[kh][kw + 1], wv, acc[oc][1]);
                }
            }
        }
    }

    #pragma unroll
    for (int oc = 0; oc < 3; ++oc) {
        const float bv = cb[oc];
        float2 o;
        o.x = tanhf(acc[oc][0] + bv);
        o.y = tanhf(acc[oc][1] + bv);
        *(float2*)(ll + (((size_t)b * 3 + oc) * H1 + h) * W1 + w0) = o;
    }
}

// Fused double inverse-Haar:
// each thread: one coarse pixel (b,c,h,w) -> 4x4 output block at (4h,4w).
__global__ __launch_bounds__(256) void iwt2_kernel(
    const float* __restrict__ ll,    // [16,3,128,128]
    const float* __restrict__ hf2,   // [16,9,128,128]
    const float* __restrict__ hf1,   // [16,9,256,256]
    float* __restrict__ out)         // [16,3,512,512]
{
    const int idx = blockIdx.x * 256 + threadIdx.x;   // 786432 total
    const int w = idx & (W1 - 1);
    const int h = (idx >> 7) & (H1 - 1);
    const int rest = idx >> 14;       // 0..47
    const int c = rest % 3;
    const int b = rest / 3;

    const float llv = ll[(((size_t)b * 3 + c) * H1 + h) * W1 + w];

    const float* h2p = hf2 + (((size_t)b * 9 + 3 * c) * H1 + h) * W1 + w;
    const float a2 = h2p[0]           * 2.f - 1.f;   // LH
    const float b2 = h2p[H1 * W1]     * 2.f - 1.f;   // HL
    const float c2 = h2p[2 * H1 * W1] * 2.f - 1.f;   // HH

    float mid[2][2];
    mid[0][0] = 0.5f * (llv - a2 - b2 + c2);
    mid[0][1] = 0.5f * (llv - a2 + b2 - c2);
    mid[1][0] = 0.5f * (llv + a2 - b2 - c2);
    mid[1][1] = 0.5f * (llv + a2 + b2 + c2);

    const float* h1b = hf1 + ((size_t)b * 9 + 3 * c) * H2 * W2;
    float* ob = out + (((size_t)b * 3 + c) * H3) * W3;

    #pragma unroll
    for (int p = 0; p < 2; ++p) {
        const int Hr = 2 * h + p;
        const float* rowp = h1b + Hr * W2 + 2 * w;
        const float2 a1 = *(const float2*)(rowp);                 // LH: q=0 (.x), q=1 (.y)
        const float2 b1 = *(const float2*)(rowp + H2 * W2);       // HL
        const float2 c1 = *(const float2*)(rowp + 2 * H2 * W2);   // HH
        const float ax = a1.x * 2.f - 1.f, ay = a1.y * 2.f - 1.f;
        const float bx = b1.x * 2.f - 1.f, by = b1.y * 2.f - 1.f;
        const float cx = c1.x * 2.f - 1.f, cy = c1.y * 2.f - 1.f;
        #pragma unroll
        for (int r = 0; r < 2; ++r) {
            const float sr = r ? 1.f : -1.f;
            float4 o;
            // cols 4w .. 4w+3 == (q=0,s=0),(q=0,s=1),(q=1,s=0),(q=1,s=1)
            o.x = 0.5f * (mid[p][0] + sr * ax - bx - sr * cx);
            o.y = 0.5f * (mid[p][0] + sr * ax + bx + sr * cx);
            o.z = 0.5f * (mid[p][1] + sr * ay - by - sr * cy);
            o.w = 0.5f * (mid[p][1] + sr * ay + by + sr * cy);
            *(float4*)(ob + (4 * h + 2 * p + r) * W3 + 4 * w) = o;
        }
    }
}

extern "C" void kernel_launch(void* const* d_in, const int* in_sizes, int n_in,
                              void* d_out, int out_size, void* d_ws, size_t ws_size,
                              hipStream_t stream) {
    (void)in_sizes; (void)n_in; (void)out_size; (void)ws_size;
    const float* fused = (const float*)d_in[0];
    const float* hf1   = (const float*)d_in[1];
    const float* hf2   = (const float*)d_in[2];
    const float* cw    = (const float*)d_in[3];
    const float* cb    = (const float*)d_in[4];
    float* out = (float*)d_out;
    float* ll  = (float*)d_ws;   // 16*3*128*128 floats = 3.1 MB

    dim3 cblk(64, 4, 1);
    dim3 cgrd(1, H1 / 4, 16);
    conv_tanh_kernel<<<cgrd, cblk, 0, stream>>>(fused, cw, cb, ll);

    const int total = 16 * 3 * H1 * W1;            // 786432
    iwt2_kernel<<<total / 256, 256, 0, stream>>>(ll, hf2, hf1, out);
}